// Round 22
// baseline (542.359 us; speedup 1.0000x reference)
//
#include <hip/hip_runtime.h>
#include <math.h>

#define BB 64
#define TT 8192
#define DD 128
#define RPT 64                   // rows per tile
#define NT 16                    // tiles per block
#define RPBLK (RPT * NT)         // 1024 rows per block
#define NBLK (BB * TT / RPBLK)   // 512 blocks (2/CU exactly)
#define BPB (TT / RPBLK)         // 8 blocks per batch row

typedef float f32x4 __attribute__((ext_vector_type(4)));
typedef __bf16 bf16x4 __attribute__((ext_vector_type(4)));
typedef __bf16 bf16x8 __attribute__((ext_vector_type(8)));

__device__ __forceinline__ float fast_tanh(float x) {
    float t = __expf(2.f * x);
    return 1.f - 2.f * __builtin_amdgcn_rcpf(t + 1.f);
}

__device__ __forceinline__ float bf_at_lo16(unsigned u) { return __uint_as_float(u << 16); }
__device__ __forceinline__ float bf_at_hi16(unsigned u) { return __uint_as_float(u & 0xffff0000u); }

// ---------------------------------------------------------------------------
// Kernel 1 (fused prep): convw (V_w f32->bf16 pre-swizzled) + fkprime.
// ---------------------------------------------------------------------------
__global__ __launch_bounds__(256) void prep_kernel(
    const float* __restrict__ Vw, const float* __restrict__ Waw,
    const float* __restrict__ Wab, const float* __restrict__ h_tm1,
    __bf16* __restrict__ Vw_bf, float* __restrict__ fkp) {
    const int b = blockIdx.x, tid = threadIdx.x;
    const int i = b * 256 + tid;
    const int r = i >> 7, cidx = i & 127;
    Vw_bf[r * DD + (cidx ^ ((r & 7) << 3))] = (__bf16)Vw[i];

    if (tid < DD) {
        const float* __restrict__ w = Waw + tid * DD;
        const float* __restrict__ h = h_tm1 + b * DD;
        float a0 = 0.f, a1 = 0.f, a2 = 0.f, a3 = 0.f;
#pragma unroll
        for (int d = 0; d < DD; d += 4) {
            float4 w4 = *reinterpret_cast<const float4*>(w + d);
            a0 = fmaf(w4.x, h[d + 0], a0);
            a1 = fmaf(w4.y, h[d + 1], a1);
            a2 = fmaf(w4.z, h[d + 2], a2);
            a3 = fmaf(w4.w, h[d + 3], a3);
        }
        fkp[b * DD + tid] = (a0 + a1) + (a2 + a3) + Wab[tid];
    }
}

// ---------------------------------------------------------------------------
// Kernel 2: R16 structure, templated for ablation.
// MODE 0 = FULL (exact R16, REPS=1, real outputs — launched LAST)
// MODE 1 = STAGE_ONLY (loads+cvt+ds_write+barrier; compute stubbed)
// MODE 2 = NO_STAGE  (compute from fixed tile; staging stubbed; barrier kept)
// MODE 3 = NO_EPI    (staging+GEMM; epilogue/z stubbed, acc kept live)
// Diag modes run REPS=4 so their dispatches exceed the harness fill kernels
// and surface in the rocprof top-5 with their own PMC rows.
// ---------------------------------------------------------------------------
template <int MODE, int REPS>
__global__ __launch_bounds__(256, 2) void beta_z_kernel(
    const float* __restrict__ H, const __bf16* __restrict__ Vw_bf,
    const float* __restrict__ Vb, const float* __restrict__ fkp,
    const float* __restrict__ vvec, const float* __restrict__ cptr,
    const int* __restrict__ mask,
    float* __restrict__ eout,
    float* __restrict__ zpart) {
    const int tid  = threadIdx.x;
    const int wv   = tid >> 6;
    const int lane = tid & 63;
    const int cl   = lane & 15;
    const int kg   = lane >> 4;
    const int base_row = blockIdx.x * RPBLK;
    const int b    = base_row >> 13;

    __shared__ __align__(16) char s_vw[DD * DD * 2];
    __shared__ __align__(16) char s_h[2][RPT * DD * 2];
    __shared__ float s_z[4][DD];

    // ---- prologue: V_w DMA ----
    {
        const char* __restrict__ wg = (const char*)Vw_bf;
#pragma unroll
        for (int i = 0; i < 8; ++i) {
            __builtin_amdgcn_global_load_lds(
                (const void*)(wg + wv * 8192 + i * 1024 + lane * 16),
                (void*)(s_vw + wv * 8192 + i * 1024), 16, 0, 0);
        }
    }
    // ---- stage tile 0 ----
    float4 hreg[8];
    {
        const float4* __restrict__ Hg =
            reinterpret_cast<const float4*>(H + (size_t)base_row * DD);
#pragma unroll
        for (int i = 0; i < 8; ++i) hreg[i] = Hg[i * 256 + tid];
#pragma unroll
        for (int i = 0; i < 8; ++i) {
            bf16x4 r;
            r[0] = (__bf16)hreg[i].x; r[1] = (__bf16)hreg[i].y;
            r[2] = (__bf16)hreg[i].z; r[3] = (__bf16)hreg[i].w;
            const int off = (i * 256 + tid) * 8;
            const int row = off >> 8;
            *reinterpret_cast<bf16x4*>(s_h[0] + (off ^ ((row & 7) << 4))) = r;
        }
    }
    __syncthreads();

    const float cval = cptr[0];
    float biasv[8], vvv[8];
#pragma unroll
    for (int nt = 0; nt < 8; ++nt) {
        const int col = nt * 16 + cl;
        biasv[nt] = Vb[col] + fkp[b * DD + col];
        vvv[nt]   = vvec[col];
    }

    const int ra   = wv * 16 + cl;
    const int swzA = (cl & 7) << 4;
    f32x4 zlo[4], zhi[4];
#pragma unroll
    for (int kk = 0; kk < 4; ++kk) {
        zlo[kk] = (f32x4){0.f, 0.f, 0.f, 0.f};
        zhi[kk] = (f32x4){0.f, 0.f, 0.f, 0.f};
    }

    for (int rep = 0; rep < REPS; ++rep) {
        for (int t = 0; t < NT; ++t) {
            const int gt  = rep * NT + t;
            const int cur = gt & 1;
            const bool havenext = (MODE == 0) ? (t + 1 < NT) : true;
            const int tnext = (t + 1 < NT) ? (t + 1) : 0;
            const int grow0  = base_row + t * RPT;
            const int myrow0 = grow0 + wv * 16;

            // ---- prefetch next tile's f32 rows ----
            if (MODE != 2 && havenext) {
                const float4* __restrict__ Hn = reinterpret_cast<const float4*>(
                    H + (size_t)(base_row + tnext * RPT) * DD);
#pragma unroll
                for (int i = 0; i < 8; ++i) hreg[i] = Hn[i * 256 + tid];
            }
            const float mfl = (float)mask[myrow0 + cl];

            if (MODE == 1) {
                // keep mask + one LDS value alive; skip compute entirely
                const unsigned kread = *reinterpret_cast<const unsigned*>(s_h[cur]);
                asm volatile("" :: "v"(mfl), "v"(kread));
            } else {
                // ---- A-frags ----
                uint4  au[4];
                bf16x8 af[4];
#pragma unroll
                for (int kk = 0; kk < 4; ++kk) {
                    const int abyte = ra * 256 + kk * 64 + kg * 16;
                    const int src   = (MODE == 2) ? 0 : cur;
                    au[kk] = *reinterpret_cast<const uint4*>(s_h[src] + (abyte ^ swzA));
                    af[kk] = __builtin_bit_cast(bf16x8, au[kk]);
                }

                // ---- GEMM ----
                f32x4 acc[8];
#pragma unroll
                for (int nt = 0; nt < 8; ++nt) acc[nt] = (f32x4){0.f, 0.f, 0.f, 0.f};
#pragma unroll
                for (int kk = 0; kk < 4; ++kk) {
#pragma unroll
                    for (int nt = 0; nt < 8; ++nt) {
                        const int rb    = nt * 16 + cl;
                        const int bbyte = (rb * 256 + kk * 64 + kg * 16) ^ ((rb & 7) << 4);
                        bf16x8 bfr = *reinterpret_cast<const bf16x8*>(s_vw + bbyte);
                        acc[nt] = __builtin_amdgcn_mfma_f32_16x16x32_bf16(af[kk], bfr, acc[nt], 0, 0, 0);
                    }
                }

                if (MODE == 3) {
                    // keep the MFMAs alive without the epilogue
#pragma unroll
                    for (int nt = 0; nt < 8; ++nt)
                        asm volatile("" :: "v"(acc[nt][0]), "v"(acc[nt][1]),
                                           "v"(acc[nt][2]), "v"(acc[nt][3]));
                } else {
                    // ---- epilogue ----
                    float part[4] = {0.f, 0.f, 0.f, 0.f};
#pragma unroll
                    for (int nt = 0; nt < 8; ++nt) {
#pragma unroll
                        for (int j = 0; j < 4; ++j)
                            part[j] = fmaf(fast_tanh(acc[nt][j] + biasv[nt]), vvv[nt], part[j]);
                    }
#pragma unroll
                    for (int off = 1; off < 16; off <<= 1) {
#pragma unroll
                        for (int j = 0; j < 4; ++j) part[j] += __shfl_xor(part[j], off);
                    }
                    float epj[4];
#pragma unroll
                    for (int j = 0; j < 4; ++j) {
                        const float mv = __shfl(mfl, kg * 4 + j);
                        const float x  = fminf(fmaxf(cval + part[j], -15.f), 15.f);
                        epj[j] = __expf(x * mv - 15.f) * mv;
                    }
                    if (cl == 0) {
#pragma unroll
                        for (int j = 0; j < 4; ++j) eout[myrow0 + kg * 4 + j] = epj[j];
                    }

                    // ---- z accumulate ----
                    const float er0 = __shfl(epj[0], (cl >> 2) << 4);
                    const float er1 = __shfl(epj[1], (cl >> 2) << 4);
                    const float er2 = __shfl(epj[2], (cl >> 2) << 4);
                    const float er3 = __shfl(epj[3], (cl >> 2) << 4);
                    const int sel = cl & 3;
                    const float e_cl = sel == 0 ? er0 : (sel == 1 ? er1 : (sel == 2 ? er2 : er3));
#pragma unroll
                    for (int kk = 0; kk < 4; ++kk) {
                        zlo[kk][0] = fmaf(e_cl, bf_at_lo16(au[kk].x), zlo[kk][0]);
                        zlo[kk][1] = fmaf(e_cl, bf_at_hi16(au[kk].x), zlo[kk][1]);
                        zlo[kk][2] = fmaf(e_cl, bf_at_lo16(au[kk].y), zlo[kk][2]);
                        zlo[kk][3] = fmaf(e_cl, bf_at_hi16(au[kk].y), zlo[kk][3]);
                        zhi[kk][0] = fmaf(e_cl, bf_at_lo16(au[kk].z), zhi[kk][0]);
                        zhi[kk][1] = fmaf(e_cl, bf_at_hi16(au[kk].z), zhi[kk][1]);
                        zhi[kk][2] = fmaf(e_cl, bf_at_lo16(au[kk].w), zhi[kk][2]);
                        zhi[kk][3] = fmaf(e_cl, bf_at_hi16(au[kk].w), zhi[kk][3]);
                    }
                }
            }

            // ---- stage next tile into other buffer ----
            if (MODE != 2 && havenext) {
#pragma unroll
                for (int i = 0; i < 8; ++i) {
                    bf16x4 r;
                    r[0] = (__bf16)hreg[i].x; r[1] = (__bf16)hreg[i].y;
                    r[2] = (__bf16)hreg[i].z; r[3] = (__bf16)hreg[i].w;
                    const int off = (i * 256 + tid) * 8;
                    const int row = off >> 8;
                    *reinterpret_cast<bf16x4*>(s_h[cur ^ 1] + (off ^ ((row & 7) << 4))) = r;
                }
            }
            __syncthreads();
        }
    }

    if (MODE == 0 || MODE == 2) {
        // ---- final z reduce + combine (FULL writes real zpart; MODE 2's
        // garbage is overwritten by the FULL dispatch launched after it) ----
#pragma unroll
        for (int off = 1; off < 16; off <<= 1) {
#pragma unroll
            for (int kk = 0; kk < 4; ++kk) {
#pragma unroll
                for (int j = 0; j < 4; ++j) {
                    zlo[kk][j] += __shfl_xor(zlo[kk][j], off);
                    zhi[kk][j] += __shfl_xor(zhi[kk][j], off);
                }
            }
        }
        if (cl == 0) {
#pragma unroll
            for (int kk = 0; kk < 4; ++kk) {
#pragma unroll
                for (int j = 0; j < 4; ++j) {
                    s_z[wv][kk * 32 + kg * 8 + j]     = zlo[kk][j];
                    s_z[wv][kk * 32 + kg * 8 + 4 + j] = zhi[kk][j];
                }
            }
        }
        __syncthreads();
        if (tid < DD) {
            zpart[(size_t)blockIdx.x * DD + tid] =
                (s_z[0][tid] + s_z[1][tid]) + (s_z[2][tid] + s_z[3][tid]);
        }
    }
}

// ---------------------------------------------------------------------------
// Kernel 3 (fused): per-b denom + normalize beta + final z.
// ---------------------------------------------------------------------------
__global__ __launch_bounds__(256) void denom_z_kernel(
    float* __restrict__ eout, const int* __restrict__ mask,
    const float* __restrict__ zpart, float* __restrict__ out_z) {
    const int b = blockIdx.x, tid = threadIdx.x;
    float* __restrict__ e = eout + (size_t)b * TT;
    const int* __restrict__ mrow = mask + (size_t)b * TT;
    __shared__ float sE[256], sM[256];
    __shared__ int sA[256];

    float E = 0.f, M = 0.f;
    int any0 = 0;
    for (int t = tid; t < TT; t += 256) {
        float ep = e[t];
        E += ep;
        M = fmaxf(M, ep);
        any0 |= (mrow[t] == 0);
    }
    sE[tid] = E; sM[tid] = M; sA[tid] = any0;
    __syncthreads();
    for (int s = 128; s > 0; s >>= 1) {
        if (tid < s) {
            sE[tid] += sE[tid + s];
            sM[tid] = fmaxf(sM[tid], sM[tid + s]);
            sA[tid] |= sA[tid + s];
        }
        __syncthreads();
    }
    const float scale = sA[0] ? fmaxf(sM[0], 3.0590232e-7f /*e^-15*/) : sM[0];
    const float dn = sE[0] + 1e-6f * scale;
    const float inv = 1.f / dn;

    for (int t = tid; t < TT; t += 256) e[t] *= inv;

    if (tid < DD) {
        const float* __restrict__ zp = zpart + (size_t)b * BPB * DD + tid;
        float s = 0.f;
#pragma unroll
        for (int cc = 0; cc < BPB; ++cc) s += zp[cc * DD];
        out_z[b * DD + tid] = s * inv;
    }
}

// ---------------------------------------------------------------------------
extern "C" void kernel_launch(void* const* d_in, const int* in_sizes, int n_in,
                              void* d_out, int out_size, void* d_ws, size_t ws_size,
                              hipStream_t stream) {
    const float* H     = (const float*)d_in[0];
    const int*   mask  = (const int*)d_in[1];
    const float* h_tm1 = (const float*)d_in[2];
    const float* V_w   = (const float*)d_in[3];
    const float* V_b   = (const float*)d_in[4];
    const float* Wa_w  = (const float*)d_in[5];
    const float* Wa_b  = (const float*)d_in[6];
    const float* v     = (const float*)d_in[7];
    const float* c     = (const float*)d_in[8];

    float* out_z    = (float*)d_out;
    float* out_beta = (float*)d_out + BB * DD;

    float* ws     = (float*)d_ws;
    float* fkp    = ws;
    float* zpart  = fkp + BB * DD;
    __bf16* Vw_bf = (__bf16*)(zpart + NBLK * DD);

    prep_kernel<<<BB, 256, 0, stream>>>(V_w, Wa_w, Wa_b, h_tm1, Vw_bf, fkp);
    // --- diagnostics (outputs overwritten by the FULL dispatch below) ---
    beta_z_kernel<1, 4><<<NBLK, 256, 0, stream>>>(H, Vw_bf, V_b, fkp, v, c, mask,
                                                  out_beta, zpart);
    beta_z_kernel<2, 4><<<NBLK, 256, 0, stream>>>(H, Vw_bf, V_b, fkp, v, c, mask,
                                                  out_beta, zpart);
    beta_z_kernel<3, 4><<<NBLK, 256, 0, stream>>>(H, Vw_bf, V_b, fkp, v, c, mask,
                                                  out_beta, zpart);
    // --- the real computation (exact R16 semantics) ---
    beta_z_kernel<0, 1><<<NBLK, 256, 0, stream>>>(H, Vw_bf, V_b, fkp, v, c, mask,
                                                  out_beta, zpart);
    denom_z_kernel<<<BB, 256, 0, stream>>>(out_beta, mask, zpart, out_z);
}

// Round 23
// 90.305 us; speedup vs baseline: 6.0058x; 6.0058x over previous
//
#include <hip/hip_runtime.h>
#include <math.h>

#define BB 64
#define TT 8192
#define DD 128
#define RPT 64                   // rows per tile
#define NT 16                    // tiles per block
#define RPBLK (RPT * NT)         // 1024 rows per block
#define NBLK (BB * TT / RPBLK)   // 512 blocks (2/CU exactly)
#define BPB (TT / RPBLK)         // 8 blocks per batch row

typedef float f32x4 __attribute__((ext_vector_type(4)));
typedef __bf16 bf16x8 __attribute__((ext_vector_type(8)));

__device__ __forceinline__ float fast_tanh(float x) {
    float t = __expf(2.f * x);
    return 1.f - 2.f * __builtin_amdgcn_rcpf(t + 1.f);
}

__device__ __forceinline__ bf16x8 cvt8(f32x4 a, f32x4 b) {
    bf16x8 r;
    r[0] = (__bf16)a[0]; r[1] = (__bf16)a[1]; r[2] = (__bf16)a[2]; r[3] = (__bf16)a[3];
    r[4] = (__bf16)b[0]; r[5] = (__bf16)b[1]; r[6] = (__bf16)b[2]; r[7] = (__bf16)b[3];
    return r;
}

// ---------------------------------------------------------------------------
// Kernel 1 (fused prep): V_w f32->bf16 PRE-SWIZZLED ((r,c)->r*128+(c^((r&7)<<3)))
// + fkprime.
// ---------------------------------------------------------------------------
__global__ __launch_bounds__(256) void prep_kernel(
    const float* __restrict__ Vw, const float* __restrict__ Waw,
    const float* __restrict__ Wab, const float* __restrict__ h_tm1,
    __bf16* __restrict__ Vw_bf, float* __restrict__ fkp) {
    const int b = blockIdx.x, tid = threadIdx.x;
    const int i = b * 256 + tid;               // 0 .. 16383
    const int r = i >> 7, cidx = i & 127;
    Vw_bf[r * DD + (cidx ^ ((r & 7) << 3))] = (__bf16)Vw[i];

    if (tid < DD) {
        const float* __restrict__ w = Waw + tid * DD;
        const float* __restrict__ h = h_tm1 + b * DD;
        float a0 = 0.f, a1 = 0.f, a2 = 0.f, a3 = 0.f;
#pragma unroll
        for (int d = 0; d < DD; d += 4) {
            float4 w4 = *reinterpret_cast<const float4*>(w + d);
            a0 = fmaf(w4.x, h[d + 0], a0);
            a1 = fmaf(w4.y, h[d + 1], a1);
            a2 = fmaf(w4.z, h[d + 2], a2);
            a3 = fmaf(w4.w, h[d + 3], a3);
        }
        fkp[b * DD + tid] = (a0 + a1) + (a2 + a3) + Wab[tid];
    }
}

// ---------------------------------------------------------------------------
// Kernel 2: lockstep single-buffer DMA pipeline (R22-ablation-driven).
// Per tile: A-frag ds_read(f32)+cvt -> barrier1 -> issue 8 global_load_lds
// for t+1 (pre-swizzled SOURCE, linear LDS dest) -> GEMM+epilogue+z (covers
// DMA latency) -> vmcnt(0) -> eout stores -> barrier2. No register staging
// (un-sinkable DMA). z from the f32 A-values. 66 KB LDS -> 2 blocks/CU.
// ---------------------------------------------------------------------------
__global__ __launch_bounds__(256, 2) void beta_z_kernel(
    const float* __restrict__ H, const __bf16* __restrict__ Vw_bf,
    const float* __restrict__ Vb, const float* __restrict__ fkp,
    const float* __restrict__ vvec, const float* __restrict__ cptr,
    const int* __restrict__ mask,
    float* __restrict__ eout,      // d_out beta region (e' before normalize)
    float* __restrict__ zpart) {   // [NBLK][DD]
    const int tid  = threadIdx.x;
    const int wv   = tid >> 6;
    const int lane = tid & 63;
    const int cl   = lane & 15;
    const int kg   = lane >> 4;
    const int base_row = blockIdx.x * RPBLK;
    const int b    = base_row >> 13; // 1024 | 8192 so block is one b

    __shared__ __align__(16) char s_vw[DD * DD * 2];  // 32 KB bf16 V_w (pre-swz)
    __shared__ __align__(16) char s_hf[RPT * DD * 4]; // 32 KB f32 H tile (swz)
    __shared__ float s_z[4][DD];                      // 2 KB

    // ---- prologue: V_w DMA + tile-0 H DMA (own quarter, pre-swz source) ----
    {
        const char* __restrict__ wg = (const char*)Vw_bf;
#pragma unroll
        for (int i = 0; i < 8; ++i) {
            __builtin_amdgcn_global_load_lds(
                (const void*)(wg + wv * 8192 + i * 1024 + lane * 16),
                (void*)(s_vw + wv * 8192 + i * 1024), 16, 0, 0);
        }
        const char* __restrict__ hb =
            (const char*)H + (size_t)(base_row + wv * 16) * 512;
#pragma unroll
        for (int i = 0; i < 8; ++i) {
            const int off = i * 1024 + lane * 16;   // within wave's 8 KB quarter
            const int r16 = off >> 9;               // row (512 B per f32 row)
            __builtin_amdgcn_global_load_lds(
                (const void*)(hb + (off ^ ((r16 & 7) << 4))),
                (void*)(s_hf + wv * 8192 + i * 1024), 16, 0, 0);
        }
    }
    __syncthreads();  // drains all prologue DMAs; s_vw + tile0 ready

    // hoisted per-lane epilogue constants
    const float cval = cptr[0];
    float biasv[8], vvv[8];
#pragma unroll
    for (int nt = 0; nt < 8; ++nt) {
        const int col = nt * 16 + cl;
        biasv[nt] = Vb[col] + fkp[b * DD + col];
        vvv[nt]   = vvec[col];
    }

    const int swzA = (cl & 7) << 4;  // row XOR; wv*16 ≡ 0 mod 8
    f32x4 zlo[4], zhi[4];            // z accum: d = kk*32 + kg*8 + {0..3, 4..7}
#pragma unroll
    for (int kk = 0; kk < 4; ++kk) {
        zlo[kk] = (f32x4){0.f, 0.f, 0.f, 0.f};
        zhi[kk] = (f32x4){0.f, 0.f, 0.f, 0.f};
    }

    for (int t = 0; t < NT; ++t) {
        const int myrow0 = base_row + t * RPT + wv * 16;
        const float mfl = (float)mask[myrow0 + cl];

        // ---- A-frags: own 16 rows, f32 (swizzled) -> cvt bf16 ----
        f32x4 alo[4], ahi[4];
        bf16x8 af[4];
#pragma unroll
        for (int kk = 0; kk < 4; ++kk) {
            const int abyte = (wv * 16 + cl) * 512 + kk * 128 + kg * 32;
            alo[kk] = *reinterpret_cast<const f32x4*>(s_hf + ((abyte)      ^ swzA));
            ahi[kk] = *reinterpret_cast<const f32x4*>(s_hf + ((abyte + 16) ^ swzA));
            af[kk]  = cvt8(alo[kk], ahi[kk]);
        }
        __syncthreads();  // barrier1: all waves' A-reads of tile t complete

        // ---- issue tile t+1's DMAs into the (now free) buffer ----
        if (t + 1 < NT) {
            const char* __restrict__ hb =
                (const char*)H + (size_t)(myrow0 + RPT) * 512;
#pragma unroll
            for (int i = 0; i < 8; ++i) {
                const int off = i * 1024 + lane * 16;
                const int r16 = off >> 9;
                __builtin_amdgcn_global_load_lds(
                    (const void*)(hb + (off ^ ((r16 & 7) << 4))),
                    (void*)(s_hf + wv * 8192 + i * 1024), 16, 0, 0);
            }
        }

        // ---- GEMM: own 16 rows x 128 cols (B from s_vw) ----
        f32x4 acc[8];
#pragma unroll
        for (int nt = 0; nt < 8; ++nt) acc[nt] = (f32x4){0.f, 0.f, 0.f, 0.f};
#pragma unroll
        for (int kk = 0; kk < 4; ++kk) {
#pragma unroll
            for (int nt = 0; nt < 8; ++nt) {
                const int rb    = nt * 16 + cl;
                const int bbyte = (rb * 256 + kk * 64 + kg * 16) ^ ((rb & 7) << 4);
                bf16x8 bfr = *reinterpret_cast<const bf16x8*>(s_vw + bbyte);
                acc[nt] = __builtin_amdgcn_mfma_f32_16x16x32_bf16(af[kk], bfr, acc[nt], 0, 0, 0);
            }
        }

        // ---- epilogue: tanh, v-weighted row-sum, butterfly, e' ----
        float part[4] = {0.f, 0.f, 0.f, 0.f};
#pragma unroll
        for (int nt = 0; nt < 8; ++nt) {
#pragma unroll
            for (int j = 0; j < 4; ++j)
                part[j] = fmaf(fast_tanh(acc[nt][j] + biasv[nt]), vvv[nt], part[j]);
        }
#pragma unroll
        for (int off = 1; off < 16; off <<= 1) {
#pragma unroll
            for (int j = 0; j < 4; ++j) part[j] += __shfl_xor(part[j], off);
        }
        float epj[4];  // e' of rows myrow0 + kg*4 + j, valid across quadrant kg
#pragma unroll
        for (int j = 0; j < 4; ++j) {
            const float mv = __shfl(mfl, kg * 4 + j);
            const float x  = fminf(fmaxf(cval + part[j], -15.f), 15.f);
            epj[j] = __expf(x * mv - 15.f) * mv;
        }

        // ---- z accumulate from f32 A registers (row cl x 32 cols) ----
        const float er0 = __shfl(epj[0], (cl >> 2) << 4);
        const float er1 = __shfl(epj[1], (cl >> 2) << 4);
        const float er2 = __shfl(epj[2], (cl >> 2) << 4);
        const float er3 = __shfl(epj[3], (cl >> 2) << 4);
        const int sel = cl & 3;
        const float e_cl = sel == 0 ? er0 : (sel == 1 ? er1 : (sel == 2 ? er2 : er3));
#pragma unroll
        for (int kk = 0; kk < 4; ++kk) {
#pragma unroll
            for (int j = 0; j < 4; ++j) {
                zlo[kk][j] = fmaf(e_cl, alo[kk][j], zlo[kk][j]);
                zhi[kk][j] = fmaf(e_cl, ahi[kk][j], zhi[kk][j]);
            }
        }

        // ---- drain DMAs (mostly complete under the compute), THEN store ----
        if (t + 1 < NT) {
            asm volatile("s_waitcnt vmcnt(0)" ::: "memory");
        }
        if (cl == 0) {
#pragma unroll
            for (int j = 0; j < 4; ++j) eout[myrow0 + kg * 4 + j] = epj[j];
        }
        __syncthreads();  // barrier2: tile t+1 visible for next A-reads
    }

    // ---- final z reduce over the 16 cl-lanes, then cross-wave combine ----
#pragma unroll
    for (int off = 1; off < 16; off <<= 1) {
#pragma unroll
        for (int kk = 0; kk < 4; ++kk) {
#pragma unroll
            for (int j = 0; j < 4; ++j) {
                zlo[kk][j] += __shfl_xor(zlo[kk][j], off);
                zhi[kk][j] += __shfl_xor(zhi[kk][j], off);
            }
        }
    }
    if (cl == 0) {
#pragma unroll
        for (int kk = 0; kk < 4; ++kk) {
#pragma unroll
            for (int j = 0; j < 4; ++j) {
                s_z[wv][kk * 32 + kg * 8 + j]     = zlo[kk][j];
                s_z[wv][kk * 32 + kg * 8 + 4 + j] = zhi[kk][j];
            }
        }
    }
    __syncthreads();
    if (tid < DD) {
        zpart[(size_t)blockIdx.x * DD + tid] =
            (s_z[0][tid] + s_z[1][tid]) + (s_z[2][tid] + s_z[3][tid]);
    }
}

// ---------------------------------------------------------------------------
// Kernel 3 (fused): per-b denom + normalize beta + final z.
// denom = sum(e') + 1e-6 * e^{gmax-15};
// e^{gmax-15} = any_masked ? max(max e', e^-15) : max e'
// ---------------------------------------------------------------------------
__global__ __launch_bounds__(256) void denom_z_kernel(
    float* __restrict__ eout, const int* __restrict__ mask,
    const float* __restrict__ zpart, float* __restrict__ out_z) {
    const int b = blockIdx.x, tid = threadIdx.x;
    float* __restrict__ e = eout + (size_t)b * TT;
    const int* __restrict__ mrow = mask + (size_t)b * TT;
    __shared__ float sE[256], sM[256];
    __shared__ int sA[256];

    float E = 0.f, M = 0.f;
    int any0 = 0;
    for (int t = tid; t < TT; t += 256) {
        float ep = e[t];
        E += ep;
        M = fmaxf(M, ep);
        any0 |= (mrow[t] == 0);
    }
    sE[tid] = E; sM[tid] = M; sA[tid] = any0;
    __syncthreads();
    for (int s = 128; s > 0; s >>= 1) {
        if (tid < s) {
            sE[tid] += sE[tid + s];
            sM[tid] = fmaxf(sM[tid], sM[tid + s]);
            sA[tid] |= sA[tid + s];
        }
        __syncthreads();
    }
    const float scale = sA[0] ? fmaxf(sM[0], 3.0590232e-7f /*e^-15*/) : sM[0];
    const float dn = sE[0] + 1e-6f * scale;
    const float inv = 1.f / dn;

    for (int t = tid; t < TT; t += 256) e[t] *= inv;

    if (tid < DD) {
        const float* __restrict__ zp = zpart + (size_t)b * BPB * DD + tid;
        float s = 0.f;
#pragma unroll
        for (int cc = 0; cc < BPB; ++cc) s += zp[cc * DD];
        out_z[b * DD + tid] = s * inv;
    }
}

// ---------------------------------------------------------------------------
extern "C" void kernel_launch(void* const* d_in, const int* in_sizes, int n_in,
                              void* d_out, int out_size, void* d_ws, size_t ws_size,
                              hipStream_t stream) {
    const float* H     = (const float*)d_in[0]; // [B,T,D] f32
    const int*   mask  = (const int*)d_in[1];   // [B,T] int32
    const float* h_tm1 = (const float*)d_in[2]; // [B,D] f32
    const float* V_w   = (const float*)d_in[3]; // [D,D] f32
    const float* V_b   = (const float*)d_in[4]; // [D] f32
    const float* Wa_w  = (const float*)d_in[5]; // [D,D] f32
    const float* Wa_b  = (const float*)d_in[6]; // [D] f32
    const float* v     = (const float*)d_in[7]; // [D] f32
    const float* c     = (const float*)d_in[8]; // [1] f32

    float* out_z    = (float*)d_out;           // B*D f32
    float* out_beta = (float*)d_out + BB * DD; // B*T f32

    float* ws     = (float*)d_ws;
    float* fkp    = ws;                       // B*D     =  8192 f32
    float* zpart  = fkp + BB * DD;            // NBLK*DD = 65536 f32
    __bf16* Vw_bf = (__bf16*)(zpart + NBLK * DD); // D*D bf16 (pre-swizzled)

    prep_kernel<<<BB, 256, 0, stream>>>(V_w, Wa_w, Wa_b, h_tm1, Vw_bf, fkp);
    beta_z_kernel<<<NBLK, 256, 0, stream>>>(H, Vw_bf, V_b, fkp, v, c, mask,
                                            out_beta, zpart);
    denom_z_kernel<<<BB, 256, 0, stream>>>(out_beta, mask, zpart, out_z);
}

// Round 24
// 82.144 us; speedup vs baseline: 6.6025x; 1.0994x over previous
//
#include <hip/hip_runtime.h>
#include <math.h>

#define BB 64
#define TT 8192
#define DD 128
#define RPT 64                   // rows per tile
#define NT 16                    // tiles per block
#define RPBLK (RPT * NT)         // 1024 rows per block
#define NBLK (BB * TT / RPBLK)   // 512 blocks (2/CU exactly)
#define BPB (TT / RPBLK)         // 8 blocks per batch row

typedef float f32x4 __attribute__((ext_vector_type(4)));
typedef __bf16 bf16x4 __attribute__((ext_vector_type(4)));
typedef __bf16 bf16x8 __attribute__((ext_vector_type(8)));

__device__ __forceinline__ float fast_tanh(float x) {
    float t = __expf(2.f * x);
    return 1.f - 2.f * __builtin_amdgcn_rcpf(t + 1.f);
}

// u = 32-bit word holding two bf16: low 16 bits = element i, high = element i+1
__device__ __forceinline__ float bf_at_lo16(unsigned u) { return __uint_as_float(u << 16); }
__device__ __forceinline__ float bf_at_hi16(unsigned u) { return __uint_as_float(u & 0xffff0000u); }

// ---------------------------------------------------------------------------
// Kernel 1 (fused prep): convw (V_w f32->bf16 pre-swizzled) + fkprime.
// ---------------------------------------------------------------------------
__global__ __launch_bounds__(256) void prep_kernel(
    const float* __restrict__ Vw, const float* __restrict__ Waw,
    const float* __restrict__ Wab, const float* __restrict__ h_tm1,
    __bf16* __restrict__ Vw_bf, float* __restrict__ fkp) {
    const int b = blockIdx.x, tid = threadIdx.x;
    const int i = b * 256 + tid;               // 0 .. 16383
    const int r = i >> 7, cidx = i & 127;
    Vw_bf[r * DD + (cidx ^ ((r & 7) << 3))] = (__bf16)Vw[i];

    if (tid < DD) {
        const float* __restrict__ w = Waw + tid * DD;
        const float* __restrict__ h = h_tm1 + b * DD;
        float a0 = 0.f, a1 = 0.f, a2 = 0.f, a3 = 0.f;
#pragma unroll
        for (int d = 0; d < DD; d += 4) {
            float4 w4 = *reinterpret_cast<const float4*>(w + d);
            a0 = fmaf(w4.x, h[d + 0], a0);
            a1 = fmaf(w4.y, h[d + 1], a1);
            a2 = fmaf(w4.z, h[d + 2], a2);
            a3 = fmaf(w4.w, h[d + 3], a3);
        }
        fkp[b * DD + tid] = (a0 + a1) + (a2 + a3) + Wab[tid];
    }
}

// ---------------------------------------------------------------------------
// Kernel 2: R16's lockstep-dbuf structure + SOFTWARE-PIPELINED EPILOGUE.
// Tile t's epilogue+z executes during tile t+1, between the prefetch issue
// and the ds_writes (inside the load shadow); sched_barrier(0x3CF) keeps the
// prefetch VMEM reads from sinking below it. Two named acc/au/mask states,
// manual unroll-by-2 (all state indices compile-time).
// ---------------------------------------------------------------------------
__global__ __launch_bounds__(256, 2) void beta_z_kernel(
    const float* __restrict__ H, const __bf16* __restrict__ Vw_bf,
    const float* __restrict__ Vb, const float* __restrict__ fkp,
    const float* __restrict__ vvec, const float* __restrict__ cptr,
    const int* __restrict__ mask,
    float* __restrict__ eout,      // d_out beta region (e' before normalize)
    float* __restrict__ zpart) {   // [NBLK][DD]
    const int tid  = threadIdx.x;
    const int wv   = tid >> 6;
    const int lane = tid & 63;
    const int cl   = lane & 15;
    const int kg   = lane >> 4;
    const int base_row = blockIdx.x * RPBLK;
    const int b    = base_row >> 13; // 1024 | 8192 so block is one b

    __shared__ __align__(16) char s_vw[DD * DD * 2];     // 32 KB bf16 V_w (pre-swz)
    __shared__ __align__(16) char s_h[2][RPT * DD * 2];  // 2 x 16 KB bf16 H tiles
    __shared__ float s_z[4][DD];                         // 2 KB

    // ---- prologue: V_w DMA (linear dest; ws copy pre-swizzled) ----
    {
        const char* __restrict__ wg = (const char*)Vw_bf;
#pragma unroll
        for (int i = 0; i < 8; ++i) {
            __builtin_amdgcn_global_load_lds(
                (const void*)(wg + wv * 8192 + i * 1024 + lane * 16),
                (void*)(s_vw + wv * 8192 + i * 1024), 16, 0, 0);
        }
    }
    // ---- stage tile 0 (cooperative): f32 loads -> cvt -> swizzled write ----
    float4 hreg[8];
    {
        const float4* __restrict__ Hg =
            reinterpret_cast<const float4*>(H + (size_t)base_row * DD);
#pragma unroll
        for (int i = 0; i < 8; ++i) hreg[i] = Hg[i * 256 + tid];
#pragma unroll
        for (int i = 0; i < 8; ++i) {
            bf16x4 r;
            r[0] = (__bf16)hreg[i].x; r[1] = (__bf16)hreg[i].y;
            r[2] = (__bf16)hreg[i].z; r[3] = (__bf16)hreg[i].w;
            const int off = (i * 256 + tid) * 8;   // byte in 16 KB tile
            const int row = off >> 8;              // 256 B per bf16 row
            *reinterpret_cast<bf16x4*>(s_h[0] + (off ^ ((row & 7) << 4))) = r;
        }
    }
    __syncthreads();  // drains V_w DMA vmcnt + tile-0 writes

    const float cval = cptr[0];
    float biasv[8], vvv[8];
#pragma unroll
    for (int nt = 0; nt < 8; ++nt) {
        const int col = nt * 16 + cl;
        biasv[nt] = Vb[col] + fkp[b * DD + col];
        vvv[nt]   = vvec[col];
    }

    const int ra   = wv * 16 + cl;
    const int swzA = (cl & 7) << 4;  // (ra&7)<<4, wv*16 ≡ 0 mod 8
    f32x4 zlo[4], zhi[4];            // z accum: d = kk*32 + kg*8 + {0..3, 4..7}
#pragma unroll
    for (int kk = 0; kk < 4; ++kk) {
        zlo[kk] = (f32x4){0.f, 0.f, 0.f, 0.f};
        zhi[kk] = (f32x4){0.f, 0.f, 0.f, 0.f};
    }

    // two pipeline states (index = tile&1, compile-time in the unrolled loop)
    f32x4 acc2[2][8];
    uint4 au2[2][4];
    float mfl2[2];

// EPILOGUE of tile with state slot S (rows myrow0 of that tile)
#define EPILOGUE(S, MYROW0)                                                     \
    {                                                                           \
        float part[4] = {0.f, 0.f, 0.f, 0.f};                                   \
        _Pragma("unroll")                                                       \
        for (int nt = 0; nt < 8; ++nt) {                                        \
            _Pragma("unroll")                                                   \
            for (int j = 0; j < 4; ++j)                                         \
                part[j] = fmaf(fast_tanh(acc2[S][nt][j] + biasv[nt]), vvv[nt],  \
                               part[j]);                                        \
        }                                                                       \
        _Pragma("unroll")                                                       \
        for (int off = 1; off < 16; off <<= 1) {                                \
            _Pragma("unroll")                                                   \
            for (int j = 0; j < 4; ++j) part[j] += __shfl_xor(part[j], off);    \
        }                                                                       \
        float epj[4];                                                           \
        _Pragma("unroll")                                                       \
        for (int j = 0; j < 4; ++j) {                                           \
            const float mv = __shfl(mfl2[S], kg * 4 + j);                       \
            const float x  = fminf(fmaxf(cval + part[j], -15.f), 15.f);         \
            epj[j] = __expf(x * mv - 15.f) * mv;                                \
        }                                                                       \
        if (cl == 0) {                                                          \
            _Pragma("unroll")                                                   \
            for (int j = 0; j < 4; ++j) eout[(MYROW0) + kg * 4 + j] = epj[j];   \
        }                                                                       \
        const float er0 = __shfl(epj[0], (cl >> 2) << 4);                       \
        const float er1 = __shfl(epj[1], (cl >> 2) << 4);                       \
        const float er2 = __shfl(epj[2], (cl >> 2) << 4);                       \
        const float er3 = __shfl(epj[3], (cl >> 2) << 4);                       \
        const int sel = cl & 3;                                                 \
        const float e_cl =                                                      \
            sel == 0 ? er0 : (sel == 1 ? er1 : (sel == 2 ? er2 : er3));         \
        _Pragma("unroll")                                                       \
        for (int kk = 0; kk < 4; ++kk) {                                        \
            zlo[kk][0] = fmaf(e_cl, bf_at_lo16(au2[S][kk].x), zlo[kk][0]);      \
            zlo[kk][1] = fmaf(e_cl, bf_at_hi16(au2[S][kk].x), zlo[kk][1]);      \
            zlo[kk][2] = fmaf(e_cl, bf_at_lo16(au2[S][kk].y), zlo[kk][2]);      \
            zlo[kk][3] = fmaf(e_cl, bf_at_hi16(au2[S][kk].y), zlo[kk][3]);      \
            zhi[kk][0] = fmaf(e_cl, bf_at_lo16(au2[S][kk].z), zhi[kk][0]);      \
            zhi[kk][1] = fmaf(e_cl, bf_at_hi16(au2[S][kk].z), zhi[kk][1]);      \
            zhi[kk][2] = fmaf(e_cl, bf_at_lo16(au2[S][kk].w), zhi[kk][2]);      \
            zhi[kk][3] = fmaf(e_cl, bf_at_hi16(au2[S][kk].w), zhi[kk][3]);      \
        }                                                                       \
    }

// one pipeline step for tile T with current slot CUR (=T&1), prev slot PRV
#define STEP(T, CUR, PRV)                                                       \
    {                                                                           \
        const int myrow0 = base_row + (T) * RPT + wv * 16;                      \
        if ((T) + 1 < NT) {                                                     \
            const float4* __restrict__ Hn = reinterpret_cast<const float4*>(    \
                H + (size_t)(base_row + ((T) + 1) * RPT) * DD);                 \
            _Pragma("unroll")                                                   \
            for (int i = 0; i < 8; ++i) hreg[i] = Hn[i * 256 + tid];            \
        }                                                                       \
        mfl2[CUR] = (float)mask[myrow0 + cl];                                   \
        /* pin VMEM reads above; VALU/MFMA/DS still free to schedule */         \
        __builtin_amdgcn_sched_barrier(0x3CF);                                  \
        if ((T) > 0) EPILOGUE(PRV, myrow0 - RPT)                                \
        _Pragma("unroll")                                                       \
        for (int kk = 0; kk < 4; ++kk) {                                        \
            const int abyte = ra * 256 + kk * 64 + kg * 16;                     \
            au2[CUR][kk] =                                                      \
                *reinterpret_cast<const uint4*>(s_h[CUR] + (abyte ^ swzA));     \
        }                                                                       \
        _Pragma("unroll")                                                       \
        for (int nt = 0; nt < 8; ++nt)                                          \
            acc2[CUR][nt] = (f32x4){0.f, 0.f, 0.f, 0.f};                        \
        _Pragma("unroll")                                                       \
        for (int kk = 0; kk < 4; ++kk) {                                        \
            const bf16x8 afk = __builtin_bit_cast(bf16x8, au2[CUR][kk]);        \
            _Pragma("unroll")                                                   \
            for (int nt = 0; nt < 8; ++nt) {                                    \
                const int rb    = nt * 16 + cl;                                 \
                const int bbyte =                                               \
                    (rb * 256 + kk * 64 + kg * 16) ^ ((rb & 7) << 4);           \
                bf16x8 bfr = *reinterpret_cast<const bf16x8*>(s_vw + bbyte);    \
                acc2[CUR][nt] = __builtin_amdgcn_mfma_f32_16x16x32_bf16(        \
                    afk, bfr, acc2[CUR][nt], 0, 0, 0);                          \
            }                                                                   \
        }                                                                       \
        if ((T) + 1 < NT) {                                                     \
            _Pragma("unroll")                                                   \
            for (int i = 0; i < 8; ++i) {                                       \
                bf16x4 r;                                                       \
                r[0] = (__bf16)hreg[i].x; r[1] = (__bf16)hreg[i].y;             \
                r[2] = (__bf16)hreg[i].z; r[3] = (__bf16)hreg[i].w;             \
                const int off = (i * 256 + tid) * 8;                            \
                const int row = off >> 8;                                       \
                *reinterpret_cast<bf16x4*>(s_h[(CUR) ^ 1] +                     \
                                           (off ^ ((row & 7) << 4))) = r;       \
            }                                                                   \
        }                                                                       \
        __syncthreads();                                                        \
    }

    for (int tp = 0; tp < NT; tp += 2) {
        STEP(tp, 0, 1)
        STEP(tp + 1, 1, 0)
    }
    // drain the pipeline: epilogue of the last tile (slot 1, tile NT-1)
    EPILOGUE(1, base_row + (NT - 1) * RPT + wv * 16)

#undef STEP
#undef EPILOGUE

    // ---- final z reduce over the 16 cl-lanes, then cross-wave combine ----
#pragma unroll
    for (int off = 1; off < 16; off <<= 1) {
#pragma unroll
        for (int kk = 0; kk < 4; ++kk) {
#pragma unroll
            for (int j = 0; j < 4; ++j) {
                zlo[kk][j] += __shfl_xor(zlo[kk][j], off);
                zhi[kk][j] += __shfl_xor(zhi[kk][j], off);
            }
        }
    }
    if (cl == 0) {
#pragma unroll
        for (int kk = 0; kk < 4; ++kk) {
#pragma unroll
            for (int j = 0; j < 4; ++j) {
                s_z[wv][kk * 32 + kg * 8 + j]     = zlo[kk][j];
                s_z[wv][kk * 32 + kg * 8 + 4 + j] = zhi[kk][j];
            }
        }
    }
    __syncthreads();
    if (tid < DD) {
        zpart[(size_t)blockIdx.x * DD + tid] =
            (s_z[0][tid] + s_z[1][tid]) + (s_z[2][tid] + s_z[3][tid]);
    }
}

// ---------------------------------------------------------------------------
// Kernel 3 (fused): per-b denom + normalize beta + final z.
// denom = sum(e') + 1e-6 * e^{gmax-15};
// e^{gmax-15} = any_masked ? max(max e', e^-15) : max e'
// ---------------------------------------------------------------------------
__global__ __launch_bounds__(256) void denom_z_kernel(
    float* __restrict__ eout, const int* __restrict__ mask,
    const float* __restrict__ zpart, float* __restrict__ out_z) {
    const int b = blockIdx.x, tid = threadIdx.x;
    float* __restrict__ e = eout + (size_t)b * TT;
    const int* __restrict__ mrow = mask + (size_t)b * TT;
    __shared__ float sE[256], sM[256];
    __shared__ int sA[256];

    float E = 0.f, M = 0.f;
    int any0 = 0;
    for (int t = tid; t < TT; t += 256) {
        float ep = e[t];
        E += ep;
        M = fmaxf(M, ep);
        any0 |= (mrow[t] == 0);
    }
    sE[tid] = E; sM[tid] = M; sA[tid] = any0;
    __syncthreads();
    for (int s = 128; s > 0; s >>= 1) {
        if (tid < s) {
            sE[tid] += sE[tid + s];
            sM[tid] = fmaxf(sM[tid], sM[tid + s]);
            sA[tid] |= sA[tid + s];
        }
        __syncthreads();
    }
    const float scale = sA[0] ? fmaxf(sM[0], 3.0590232e-7f /*e^-15*/) : sM[0];
    const float dn = sE[0] + 1e-6f * scale;
    const float inv = 1.f / dn;

    for (int t = tid; t < TT; t += 256) e[t] *= inv;

    if (tid < DD) {
        const float* __restrict__ zp = zpart + (size_t)b * BPB * DD + tid;
        float s = 0.f;
#pragma unroll
        for (int cc = 0; cc < BPB; ++cc) s += zp[cc * DD];
        out_z[b * DD + tid] = s * inv;
    }
}

// ---------------------------------------------------------------------------
extern "C" void kernel_launch(void* const* d_in, const int* in_sizes, int n_in,
                              void* d_out, int out_size, void* d_ws, size_t ws_size,
                              hipStream_t stream) {
    const float* H     = (const float*)d_in[0]; // [B,T,D] f32
    const int*   mask  = (const int*)d_in[1];   // [B,T] int32
    const float* h_tm1 = (const float*)d_in[2]; // [B,D] f32
    const float* V_w   = (const float*)d_in[3]; // [D,D] f32
    const float* V_b   = (const float*)d_in[4]; // [D] f32
    const float* Wa_w  = (const float*)d_in[5]; // [D,D] f32
    const float* Wa_b  = (const float*)d_in[6]; // [D] f32
    const float* v     = (const float*)d_in[7]; // [D] f32
    const float* c     = (const float*)d_in[8]; // [1] f32

    float* out_z    = (float*)d_out;           // B*D f32
    float* out_beta = (float*)d_out + BB * DD; // B*T f32

    float* ws     = (float*)d_ws;
    float* fkp    = ws;                       // B*D     =  8192 f32
    float* zpart  = fkp + BB * DD;            // NBLK*DD = 65536 f32
    __bf16* Vw_bf = (__bf16*)(zpart + NBLK * DD); // D*D bf16 (pre-swizzled)

    prep_kernel<<<BB, 256, 0, stream>>>(V_w, Wa_w, Wa_b, h_tm1, Vw_bf, fkp);
    beta_z_kernel<<<NBLK, 256, 0, stream>>>(H, Vw_bf, V_b, fkp, v, c, mask,
                                            out_beta, zpart);
    denom_z_kernel<<<BB, 256, 0, stream>>>(out_beta, mask, zpart, out_z);
}